// Round 3
// baseline (87.883 us; speedup 1.0000x reference)
//
#include <hip/hip_runtime.h>
#include <hip/hip_bf16.h>
#include <math.h>

constexpr int D      = 2048;
constexpr int NE     = 64;
constexpr int TOKENS = 16384;   // 4*4096
constexpr int TPB    = 16;      // tokens per block
constexpr int NWAVE  = 8;       // k-split waves per block
constexpr int KSLICE = D / NWAVE;   // 256 k per wave
constexpr int KC     = 32;      // k per MFMA
constexpr int PAD    = 66;      // LDS row pad: 2-way max on partial stores (free)

typedef __attribute__((ext_vector_type(8))) short bf16x8;
typedef __attribute__((ext_vector_type(4))) float f32x4;

static __device__ inline unsigned short f2bf_u(float x) {
  __hip_bfloat16 h = __float2bfloat16(x);   // RNE
  unsigned short u; __builtin_memcpy(&u, &h, 2); return u;
}
static __device__ inline float bfu2f(unsigned short u) {
  __hip_bfloat16 h; __builtin_memcpy(&h, &u, 2);
  return __bfloat162float(h);
}

// split 8 f32 into hi/lo bf16 fragments (exact to ~2^-26 rel) — same arithmetic as round 2
static __device__ inline void cvt_hilo(const float* f, bf16x8& hi, bf16x8& lo) {
#pragma unroll
  for (int j = 0; j < 8; ++j) {
    unsigned short h = f2bf_u(f[j]);
    float hf = bfu2f(h);
    unsigned short lw = f2bf_u(f[j] - hf);
    hi[j] = (short)h;
    lo[j] = (short)lw;
  }
}

// ---- pre-kernel: W (64x2048 f32) -> Whi/Wlo bf16, bit-identical to cvt_hilo ----
__global__ __launch_bounds__(256)
void prep_w(const float* __restrict__ W, unsigned short* __restrict__ Whi,
            unsigned short* __restrict__ Wlo) {
  const int i = (blockIdx.x * 256 + threadIdx.x) * 4;   // 4 elems/thread
  float4 v = *reinterpret_cast<const float4*>(W + i);
  float f[4] = {v.x, v.y, v.z, v.w};
#pragma unroll
  for (int j = 0; j < 4; ++j) {
    unsigned short h = f2bf_u(f[j]);
    float hf = bfu2f(h);
    Whi[i + j] = h;
    Wlo[i + j] = f2bf_u(f[j] - hf);
  }
}

__global__ __launch_bounds__(512, 6)
void router_main(const float* __restrict__ X,
                 const unsigned short* __restrict__ Whi,
                 const unsigned short* __restrict__ Wlo,
                 const float* __restrict__ bias,
                 float* __restrict__ out) {
  __shared__ float red[NWAVE][TPB][PAD];   // 33.8 KB
  __shared__ float lgb[TPB][PAD];          //  4.2 KB
  __shared__ int   i1s[TPB], i2s[TPB];
  __shared__ float p1s[TPB], p2s[TPB];

  const int t  = threadIdx.x;
  const int w  = t >> 6;        // wave id = k-slice
  const int l  = t & 63;
  const int lm = l & 15;        // M-row / N-col in 16x16 tile
  const int lk = l >> 4;        // k-group -> k offset lk*8
  const int tok0 = blockIdx.x * TPB;

  f32x4 acc[4];
#pragma unroll
  for (int n = 0; n < 4; ++n) acc[n] = (f32x4){0.f, 0.f, 0.f, 0.f};

  const float*          xrow = X   + (size_t)(tok0 + lm) * D + w * KSLICE + lk * 8;
  const unsigned short* whp  = Whi + (size_t)lm * D + w * KSLICE + lk * 8;
  const unsigned short* wlp  = Wlo + (size_t)lm * D + w * KSLICE + lk * 8;

  float4 a0 = *reinterpret_cast<const float4*>(xrow);
  float4 a1 = *reinterpret_cast<const float4*>(xrow + 4);

  for (int kc = 0; kc < KSLICE / KC; ++kc) {
    float f[8];
    *reinterpret_cast<float4*>(&f[0]) = a0;
    *reinterpret_cast<float4*>(&f[4]) = a1;
    if (kc < KSLICE / KC - 1) {               // prefetch next X chunk
      a0 = *reinterpret_cast<const float4*>(xrow + (kc + 1) * KC);
      a1 = *reinterpret_cast<const float4*>(xrow + (kc + 1) * KC + 4);
    }
    bf16x8 ah, al;
    cvt_hilo(f, ah, al);
    const int ko = kc * KC;
#pragma unroll
    for (int n = 0; n < 4; ++n) {             // same hh,hl,lh,ll order as round 2
      bf16x8 bh = *reinterpret_cast<const bf16x8*>(whp + (size_t)n * 16 * D + ko);
      bf16x8 bl = *reinterpret_cast<const bf16x8*>(wlp + (size_t)n * 16 * D + ko);
      acc[n] = __builtin_amdgcn_mfma_f32_16x16x32_bf16(ah, bh, acc[n], 0, 0, 0);
      acc[n] = __builtin_amdgcn_mfma_f32_16x16x32_bf16(ah, bl, acc[n], 0, 0, 0);
      acc[n] = __builtin_amdgcn_mfma_f32_16x16x32_bf16(al, bh, acc[n], 0, 0, 0);
      acc[n] = __builtin_amdgcn_mfma_f32_16x16x32_bf16(al, bl, acc[n], 0, 0, 0);
    }
  }

  // stash k-partials: C row = lk*4+j (token), col = n*16+lm (expert)  [m89 layout]
#pragma unroll
  for (int n = 0; n < 4; ++n)
#pragma unroll
    for (int j = 0; j < 4; ++j)
      red[w][lk * 4 + j][n * 16 + lm] = acc[n][j];
  __syncthreads();

  // cross-wave reduce + bias: 512 thr x 2 outputs each (same summation order as round 2)
  {
    const int tok = t >> 5;
    const int e0  = (t & 31) * 2;
#pragma unroll
    for (int q = 0; q < 2; ++q) {
      const int e = e0 + q;
      float s = bias[e];
#pragma unroll
      for (int ww = 0; ww < NWAVE; ++ww) s += red[ww][tok][e];
      lgb[tok][e] = s;
    }
  }
  __syncthreads();

  // top-2 + softmax weights (threads 0..15, one token each)
  if (t < TPB) {
    float m1 = -INFINITY, m2 = -INFINITY;
    int j1 = 0, j2 = 0;
    for (int e = 0; e < NE; ++e) {
      const float v = lgb[t][e];
      if (v > m1) { m2 = m1; j2 = j1; m1 = v; j1 = e; }     // strict >: lax.top_k tie-break
      else if (v > m2) { m2 = v; j2 = e; }
    }
    const float e2  = expf(m2 - m1);
    const float inv = 1.0f / (1.0f + e2);
    i1s[t] = j1; i2s[t] = j2;
    p1s[t] = inv; p2s[t] = e2 * inv;
    float* oidx = out + (size_t)TOKENS * NE + (size_t)(tok0 + t) * 2;
    oidx[0] = (float)j1;
    oidx[1] = (float)j2;
  }
  __syncthreads();

  // coalesced sf write: first 256 threads -> (token = t>>4, experts 4*(t&15)..+3)
  if (t < 256) {
    const int tok = t >> 4;
    const int e0  = (t & 15) * 4;
    const int j1 = i1s[tok], j2 = i2s[tok];
    const float pa = p1s[tok], pb = p2s[tok];
    float vv[4];
#pragma unroll
    for (int q = 0; q < 4; ++q) {
      const int e = e0 + q;
      vv[q] = (e == j1) ? pa : ((e == j2) ? pb : 0.f);
    }
    *reinterpret_cast<float4*>(out + (size_t)(tok0 + tok) * NE + e0) =
        make_float4(vv[0], vv[1], vv[2], vv[3]);
  }
}

extern "C" void kernel_launch(void* const* d_in, const int* in_sizes, int n_in,
                              void* d_out, int out_size, void* d_ws, size_t ws_size,
                              hipStream_t stream) {
  const float* X = (const float*)d_in[0];
  const float* W = (const float*)d_in[1];
  const float* B = (const float*)d_in[2];
  float* out = (float*)d_out;

  unsigned short* Whi = (unsigned short*)d_ws;               // 64*2048*2 B
  unsigned short* Wlo = Whi + (size_t)NE * D;                // +256 KB

  prep_w<<<dim3(NE * D / (256 * 4)), dim3(256), 0, stream>>>(W, Whi, Wlo);
  router_main<<<dim3(TOKENS / TPB), dim3(512), 0, stream>>>(X, Whi, Wlo, B, out);
}

// Round 4
// 87.551 us; speedup vs baseline: 1.0038x; 1.0038x over previous
//
#include <hip/hip_runtime.h>
#include <hip/hip_bf16.h>
#include <math.h>

constexpr int D      = 2048;
constexpr int NE     = 64;
constexpr int TOKENS = 16384;   // 4*4096
constexpr int TPB    = 16;      // tokens per block
constexpr int NWAVE  = 8;       // k-split waves per block
constexpr int KSLICE = D / NWAVE;   // 256 k per wave
constexpr int KC     = 32;      // k per MFMA
constexpr int NKC    = KSLICE / KC; // 8
constexpr int PAD    = 66;      // partial-stash is exactly 2-way (free)

typedef __attribute__((ext_vector_type(8))) short bf16x8;
typedef __attribute__((ext_vector_type(4))) float f32x4;

static __device__ inline unsigned short f2bf_u(float x) {
  __hip_bfloat16 h = __float2bfloat16(x);   // RNE
  unsigned short u; __builtin_memcpy(&u, &h, 2); return u;
}
static __device__ inline float bfu2f(unsigned short u) {
  __hip_bfloat16 h; __builtin_memcpy(&h, &u, 2);
  return __bfloat162float(h);
}

// split 8 f32 into hi/lo bf16 (same arithmetic as rounds 2/3 — keep bit-identical)
static __device__ inline void cvt_hilo(const float* f, bf16x8& hi, bf16x8& lo) {
#pragma unroll
  for (int j = 0; j < 8; ++j) {
    unsigned short h = f2bf_u(f[j]);
    float hf = bfu2f(h);
    unsigned short lw = f2bf_u(f[j] - hf);
    hi[j] = (short)h;
    lo[j] = (short)lw;
  }
}

// pre-kernel: W (64x2048 f32) -> Whi/Wlo bf16 (bit-identical split)
__global__ __launch_bounds__(256)
void prep_w(const float* __restrict__ W, unsigned short* __restrict__ Whi,
            unsigned short* __restrict__ Wlo) {
  const int i = (blockIdx.x * 256 + threadIdx.x) * 4;
  float4 v = *reinterpret_cast<const float4*>(W + i);
  float f[4] = {v.x, v.y, v.z, v.w};
#pragma unroll
  for (int j = 0; j < 4; ++j) {
    unsigned short h = f2bf_u(f[j]);
    float hf = bfu2f(h);
    Whi[i + j] = h;
    Wlo[i + j] = f2bf_u(f[j] - hf);
  }
}

__global__ __launch_bounds__(512, 8)   // force VGPR<=64 -> 32 waves/CU (structure needs ~50)
void router_main(const float* __restrict__ X,
                 const unsigned short* __restrict__ Whi,
                 const unsigned short* __restrict__ Wlo,
                 const float* __restrict__ bias,
                 float* __restrict__ out) {
  // half-size stash used twice (waves 0-3 then 4-7) -> 16.9 KB, 4 blocks/CU
  __shared__ float red[4][TPB][PAD];
  __shared__ int   i1s[TPB], i2s[TPB];
  __shared__ float p1s[TPB], p2s[TPB];

  const int t  = threadIdx.x;
  const int w  = t >> 6;        // wave id = k-slice
  const int l  = t & 63;
  const int lm = l & 15;        // M-row / N-col in 16x16 tile
  const int lk = l >> 4;        // k-group -> k offset lk*8
  const int tok0 = blockIdx.x * TPB;

  f32x4 acc[4];
#pragma unroll
  for (int n = 0; n < 4; ++n) acc[n] = (f32x4){0.f, 0.f, 0.f, 0.f};

  const float*          xrow = X   + (size_t)(tok0 + lm) * D + w * KSLICE + lk * 8;
  const unsigned short* whp  = Whi + (size_t)lm * D + w * KSLICE + lk * 8;
  const unsigned short* wlp  = Wlo + (size_t)lm * D + w * KSLICE + lk * 8;

  float f[8];
  *reinterpret_cast<float4*>(&f[0]) = *reinterpret_cast<const float4*>(xrow);
  *reinterpret_cast<float4*>(&f[4]) = *reinterpret_cast<const float4*>(xrow + 4);

  for (int kc = 0; kc < NKC; ++kc) {
    bf16x8 ah, al;
    cvt_hilo(f, ah, al);
    if (kc < NKC - 1) {                       // prefetch next X chunk (in flight over MFMAs)
      *reinterpret_cast<float4*>(&f[0]) = *reinterpret_cast<const float4*>(xrow + (kc + 1) * KC);
      *reinterpret_cast<float4*>(&f[4]) = *reinterpret_cast<const float4*>(xrow + (kc + 1) * KC + 4);
    }
    const int ko = kc * KC;
#pragma unroll
    for (int n = 0; n < 4; ++n) {             // same hh,hl,lh,ll order as rounds 2/3
      bf16x8 bh = *reinterpret_cast<const bf16x8*>(whp + (size_t)n * 16 * D + ko);
      bf16x8 bl = *reinterpret_cast<const bf16x8*>(wlp + (size_t)n * 16 * D + ko);
      acc[n] = __builtin_amdgcn_mfma_f32_16x16x32_bf16(ah, bh, acc[n], 0, 0, 0);
      acc[n] = __builtin_amdgcn_mfma_f32_16x16x32_bf16(ah, bl, acc[n], 0, 0, 0);
      acc[n] = __builtin_amdgcn_mfma_f32_16x16x32_bf16(al, bh, acc[n], 0, 0, 0);
      acc[n] = __builtin_amdgcn_mfma_f32_16x16x32_bf16(al, bl, acc[n], 0, 0, 0);
    }
  }

  // ---- two-batch cross-wave reduce; preserves bias + p0+p1+...+p7 order ----
  const int rtok = t >> 5;          // 0..15
  const int re0  = (t & 31) * 2;    // 0..62
  float s[2];

  if (w < 4) {                       // batch 1: waves 0..3 stash
#pragma unroll
    for (int n = 0; n < 4; ++n)
#pragma unroll
      for (int j = 0; j < 4; ++j)
        red[w][lk * 4 + j][n * 16 + lm] = acc[n][j];
  }
  __syncthreads();
#pragma unroll
  for (int q = 0; q < 2; ++q) {
    const int e = re0 + q;
    float v = bias[e];
#pragma unroll
    for (int ww = 0; ww < 4; ++ww) v += red[ww][rtok][e];
    s[q] = v;
  }
  __syncthreads();
  if (w >= 4) {                      // batch 2: waves 4..7 stash (same buffer)
#pragma unroll
    for (int n = 0; n < 4; ++n)
#pragma unroll
      for (int j = 0; j < 4; ++j)
        red[w - 4][lk * 4 + j][n * 16 + lm] = acc[n][j];
  }
  __syncthreads();
#pragma unroll
  for (int q = 0; q < 2; ++q) {
    const int e = re0 + q;
    float v = s[q];
#pragma unroll
    for (int ww = 0; ww < 4; ++ww) v += red[ww][rtok][e];
    // stash final logit into own slot of red[0] (this thread already consumed it; 1:1 slots)
    red[0][rtok][e] = v;
  }
  __syncthreads();

  // ---- top-2 + softmax weights (threads 0..15, one token each) ----
  if (t < TPB) {
    float m1 = -INFINITY, m2 = -INFINITY;
    int j1 = 0, j2 = 0;
    for (int e = 0; e < NE; ++e) {
      const float v = red[0][t][e];
      if (v > m1) { m2 = m1; j2 = j1; m1 = v; j1 = e; }     // strict >: lax.top_k tie-break
      else if (v > m2) { m2 = v; j2 = e; }
    }
    const float e2  = expf(m2 - m1);
    const float inv = 1.0f / (1.0f + e2);
    i1s[t] = j1; i2s[t] = j2;
    p1s[t] = inv; p2s[t] = e2 * inv;
    float* oidx = out + (size_t)TOKENS * NE + (size_t)(tok0 + t) * 2;
    oidx[0] = (float)j1;
    oidx[1] = (float)j2;
  }
  __syncthreads();

  // ---- coalesced sf write: threads 0..255 -> (token = t>>4, experts 4*(t&15)..+3) ----
  if (t < 256) {
    const int tok = t >> 4;
    const int e0  = (t & 15) * 4;
    const int j1 = i1s[tok], j2 = i2s[tok];
    const float pa = p1s[tok], pb = p2s[tok];
    float vv[4];
#pragma unroll
    for (int q = 0; q < 4; ++q) {
      const int e = e0 + q;
      vv[q] = (e == j1) ? pa : ((e == j2) ? pb : 0.f);
    }
    *reinterpret_cast<float4*>(out + (size_t)(tok0 + tok) * NE + e0) =
        make_float4(vv[0], vv[1], vv[2], vv[3]);
  }
}

extern "C" void kernel_launch(void* const* d_in, const int* in_sizes, int n_in,
                              void* d_out, int out_size, void* d_ws, size_t ws_size,
                              hipStream_t stream) {
  const float* X = (const float*)d_in[0];
  const float* W = (const float*)d_in[1];
  const float* B = (const float*)d_in[2];
  float* out = (float*)d_out;

  unsigned short* Whi = (unsigned short*)d_ws;     // 256 KB
  unsigned short* Wlo = Whi + (size_t)NE * D;      // 256 KB

  prep_w<<<dim3(NE * D / (256 * 4)), dim3(256), 0, stream>>>(W, Whi, Wlo);
  router_main<<<dim3(TOKENS / TPB), dim3(512), 0, stream>>>(X, Whi, Wlo, B, out);
}

// Round 5
// 60.546 us; speedup vs baseline: 1.4515x; 1.4460x over previous
//
#include <hip/hip_runtime.h>
#include <hip/hip_bf16.h>
#include <math.h>

constexpr int D      = 2048;
constexpr int NE     = 64;
constexpr int TOKENS = 16384;   // 4*4096
constexpr int TPB    = 32;      // tokens per block (W traffic = 512KB * TOKENS/TPB = 256 MB)
constexpr int NWAVE  = 8;       // k-split waves
constexpr int KSLICE = D / NWAVE;   // 256
constexpr int KC     = 32;      // k per MFMA step
constexpr int NKC    = KSLICE / KC; // 8
constexpr int PAD    = 66;      // stash pattern -> 2-way max (free)

typedef __attribute__((ext_vector_type(8))) short bf16x8;
typedef __attribute__((ext_vector_type(4))) float f32x4;

static __device__ inline unsigned short f2bf_u(float x) {
  __hip_bfloat16 h = __float2bfloat16(x);   // RNE
  unsigned short u; __builtin_memcpy(&u, &h, 2); return u;
}
static __device__ inline float bfu2f(unsigned short u) {
  __hip_bfloat16 h; __builtin_memcpy(&h, &u, 2);
  return __bfloat162float(h);
}

// split 8 f32 into hi/lo bf16 — bit-identical to rounds 2-4
static __device__ inline void cvt_hilo(const float* f, bf16x8& hi, bf16x8& lo) {
#pragma unroll
  for (int j = 0; j < 8; ++j) {
    unsigned short h = f2bf_u(f[j]);
    float hf = bfu2f(h);
    unsigned short lw = f2bf_u(f[j] - hf);
    hi[j] = (short)h;
    lo[j] = (short)lw;
  }
}

// pre-kernel: W (64x2048 f32) -> Whi/Wlo bf16 (bit-identical split)
__global__ __launch_bounds__(256)
void prep_w(const float* __restrict__ W, unsigned short* __restrict__ Whi,
            unsigned short* __restrict__ Wlo) {
  const int i = (blockIdx.x * 256 + threadIdx.x) * 4;
  float4 v = *reinterpret_cast<const float4*>(W + i);
  float f[4] = {v.x, v.y, v.z, v.w};
#pragma unroll
  for (int j = 0; j < 4; ++j) {
    unsigned short h = f2bf_u(f[j]);
    float hf = bfu2f(h);
    Whi[i + j] = h;
    Wlo[i + j] = f2bf_u(f[j] - hf);
  }
}

__global__ __launch_bounds__(512, 4)
void router_main(const float* __restrict__ X,
                 const unsigned short* __restrict__ Whi,
                 const unsigned short* __restrict__ Wlo,
                 const float* __restrict__ bias,
                 float* __restrict__ out) {
  __shared__ float red[4][TPB][PAD];   // 33.8 KB, used twice (waves 0-3 then 4-7)
  __shared__ int   i1s[TPB], i2s[TPB];
  __shared__ float p1s[TPB], p2s[TPB];

  const int t  = threadIdx.x;
  const int w  = t >> 6;        // wave id = k-slice
  const int l  = t & 63;
  const int lm = l & 15;        // M-row / N-col in 16x16 tile
  const int lk = l >> 4;        // k-group -> k offset lk*8
  const int tok0 = blockIdx.x * TPB;

  f32x4 acc[2][4];
#pragma unroll
  for (int m = 0; m < 2; ++m)
#pragma unroll
    for (int n = 0; n < 4; ++n) acc[m][n] = (f32x4){0.f, 0.f, 0.f, 0.f};

  const unsigned short* whp = Whi + (size_t)lm * D + w * KSLICE + lk * 8;
  const unsigned short* wlp = Wlo + (size_t)lm * D + w * KSLICE + lk * 8;
  const float* xr0 = X + (size_t)(tok0 + lm) * D      + w * KSLICE + lk * 8;
  const float* xr1 = X + (size_t)(tok0 + 16 + lm) * D + w * KSLICE + lk * 8;

  // X staging, double-buffered one kc ahead
  float4 cA0 = *reinterpret_cast<const float4*>(xr0);
  float4 cA1 = *reinterpret_cast<const float4*>(xr0 + 4);
  float4 cB0 = *reinterpret_cast<const float4*>(xr1);
  float4 cB1 = *reinterpret_cast<const float4*>(xr1 + 4);

#pragma unroll
  for (int kc = 0; kc < NKC; ++kc) {
    const int ko = kc * KC;

    // ---- batched B loads: 8 independent dwordx4, all in flight together ----
    bf16x8 bh[4], bl[4];
#pragma unroll
    for (int n = 0; n < 4; ++n) {
      bh[n] = *reinterpret_cast<const bf16x8*>(whp + (size_t)n * 16 * D + ko);
      bl[n] = *reinterpret_cast<const bf16x8*>(wlp + (size_t)n * 16 * D + ko);
    }

    // ---- prefetch next-kc X (issued before any consumption) ----
    float4 nA0, nA1, nB0, nB1;
    if (kc < NKC - 1) {
      nA0 = *reinterpret_cast<const float4*>(xr0 + (kc + 1) * KC);
      nA1 = *reinterpret_cast<const float4*>(xr0 + (kc + 1) * KC + 4);
      nB0 = *reinterpret_cast<const float4*>(xr1 + (kc + 1) * KC);
      nB1 = *reinterpret_cast<const float4*>(xr1 + (kc + 1) * KC + 4);
    }

    // ---- m = 0 ----
    {
      float f[8];
      *reinterpret_cast<float4*>(&f[0]) = cA0;
      *reinterpret_cast<float4*>(&f[4]) = cA1;
      bf16x8 ah, al;
      cvt_hilo(f, ah, al);
#pragma unroll
      for (int n = 0; n < 4; ++n) {           // same hh,hl,lh,ll order as rounds 2-4
        acc[0][n] = __builtin_amdgcn_mfma_f32_16x16x32_bf16(ah, bh[n], acc[0][n], 0, 0, 0);
        acc[0][n] = __builtin_amdgcn_mfma_f32_16x16x32_bf16(ah, bl[n], acc[0][n], 0, 0, 0);
        acc[0][n] = __builtin_amdgcn_mfma_f32_16x16x32_bf16(al, bh[n], acc[0][n], 0, 0, 0);
        acc[0][n] = __builtin_amdgcn_mfma_f32_16x16x32_bf16(al, bl[n], acc[0][n], 0, 0, 0);
      }
    }
    // ---- m = 1 ----
    {
      float f[8];
      *reinterpret_cast<float4*>(&f[0]) = cB0;
      *reinterpret_cast<float4*>(&f[4]) = cB1;
      bf16x8 ah, al;
      cvt_hilo(f, ah, al);
#pragma unroll
      for (int n = 0; n < 4; ++n) {
        acc[1][n] = __builtin_amdgcn_mfma_f32_16x16x32_bf16(ah, bh[n], acc[1][n], 0, 0, 0);
        acc[1][n] = __builtin_amdgcn_mfma_f32_16x16x32_bf16(ah, bl[n], acc[1][n], 0, 0, 0);
        acc[1][n] = __builtin_amdgcn_mfma_f32_16x16x32_bf16(al, bh[n], acc[1][n], 0, 0, 0);
        acc[1][n] = __builtin_amdgcn_mfma_f32_16x16x32_bf16(al, bl[n], acc[1][n], 0, 0, 0);
      }
    }
    if (kc < NKC - 1) { cA0 = nA0; cA1 = nA1; cB0 = nB0; cB1 = nB1; }
  }

  // ---- two-batch cross-wave reduce; preserves bias + w0+...+w7 order exactly ----
  const int rtok = t >> 4;          // 0..31
  const int re0  = (t & 15) * 4;    // 0..60
  float s[4];

  if (w < 4) {                       // batch 1: waves 0..3 stash
#pragma unroll
    for (int m = 0; m < 2; ++m)
#pragma unroll
      for (int n = 0; n < 4; ++n)
#pragma unroll
        for (int j = 0; j < 4; ++j)
          red[w][m * 16 + lk * 4 + j][n * 16 + lm] = acc[m][n][j];
  }
  __syncthreads();
#pragma unroll
  for (int q = 0; q < 4; ++q) {
    const int e = re0 + q;
    float v = bias[e];
#pragma unroll
    for (int ww = 0; ww < 4; ++ww) v += red[ww][rtok][e];
    s[q] = v;
  }
  __syncthreads();
  if (w >= 4) {                      // batch 2: waves 4..7 stash (same buffer)
#pragma unroll
    for (int m = 0; m < 2; ++m)
#pragma unroll
      for (int n = 0; n < 4; ++n)
#pragma unroll
        for (int j = 0; j < 4; ++j)
          red[w - 4][m * 16 + lk * 4 + j][n * 16 + lm] = acc[m][n][j];
  }
  __syncthreads();
#pragma unroll
  for (int q = 0; q < 4; ++q) {
    const int e = re0 + q;
    float v = s[q];
#pragma unroll
    for (int ww = 0; ww < 4; ++ww) v += red[ww][rtok][e];
    red[0][rtok][e] = v;             // 1:1 slot ownership (this thread read these slots)
  }
  __syncthreads();

  // ---- top-2 + softmax weights (threads 0..31, one token each) ----
  if (t < TPB) {
    float m1 = -INFINITY, m2 = -INFINITY;
    int j1 = 0, j2 = 0;
    for (int e = 0; e < NE; ++e) {
      const float v = red[0][t][e];
      if (v > m1) { m2 = m1; j2 = j1; m1 = v; j1 = e; }     // strict >: lax.top_k tie-break
      else if (v > m2) { m2 = v; j2 = e; }
    }
    const float e2  = expf(m2 - m1);
    const float inv = 1.0f / (1.0f + e2);
    i1s[t] = j1; i2s[t] = j2;
    p1s[t] = inv; p2s[t] = e2 * inv;
    float* oidx = out + (size_t)TOKENS * NE + (size_t)(tok0 + t) * 2;
    oidx[0] = (float)j1;
    oidx[1] = (float)j2;
  }
  __syncthreads();

  // ---- coalesced sf write: 512 thr -> (token = t>>4, experts 4*(t&15)..+3) ----
  {
    const int tok = t >> 4;
    const int e0  = (t & 15) * 4;
    const int j1 = i1s[tok], j2 = i2s[tok];
    const float pa = p1s[tok], pb = p2s[tok];
    float vv[4];
#pragma unroll
    for (int q = 0; q < 4; ++q) {
      const int e = e0 + q;
      vv[q] = (e == j1) ? pa : ((e == j2) ? pb : 0.f);
    }
    *reinterpret_cast<float4*>(out + (size_t)(tok0 + tok) * NE + e0) =
        make_float4(vv[0], vv[1], vv[2], vv[3]);
  }
}

extern "C" void kernel_launch(void* const* d_in, const int* in_sizes, int n_in,
                              void* d_out, int out_size, void* d_ws, size_t ws_size,
                              hipStream_t stream) {
  const float* X = (const float*)d_in[0];
  const float* W = (const float*)d_in[1];
  const float* B = (const float*)d_in[2];
  float* out = (float*)d_out;

  unsigned short* Whi = (unsigned short*)d_ws;     // 256 KB
  unsigned short* Wlo = Whi + (size_t)NE * D;      // 256 KB

  prep_w<<<dim3(NE * D / (256 * 4)), dim3(256), 0, stream>>>(W, Whi, Wlo);
  router_main<<<dim3(TOKENS / TPB), dim3(512), 0, stream>>>(X, Whi, Wlo, B, out);
}